// Round 6
// baseline (84175.574 us; speedup 1.0000x reference)
//
#include <hip/hip_runtime.h>
#include <math.h>

#define T_SEQ 2000
#define BATCH 32
#define NSEG  100

typedef unsigned short bf16_t;   // raw bf16 storage

__device__ __forceinline__ float sigmoidf_(float x) {
    return 1.0f / (1.0f + __expf(-x));
}
__device__ __forceinline__ float tanh_(float x) {
    return 1.0f - 2.0f / (__expf(2.0f * x) + 1.0f);
}
__device__ __forceinline__ float bf2f(bf16_t u) {
    return __uint_as_float((unsigned)u << 16);
}
__device__ __forceinline__ bf16_t f2bf(float f) {   // round-to-nearest-even
    unsigned x = __float_as_uint(f);
    return (bf16_t)((x + 0x7FFFu + ((x >> 16) & 1u)) >> 16);
}
__device__ __forceinline__ float bflo(unsigned w) { return __uint_as_float(w << 16); }
__device__ __forceinline__ float bfhi(unsigned w) { return __uint_as_float(w & 0xFFFF0000u); }

// 4 consecutive elements -> float4 (fp32 or bf16 source)
__device__ __forceinline__ float4 ld4(const float* p) { return *(const float4*)p; }
__device__ __forceinline__ float4 ld4(const bf16_t* p) {
    ushort4 u = *(const ushort4*)p;
    return make_float4(bf2f(u.x), bf2f(u.y), bf2f(u.z), bf2f(u.w));
}

// ---------------------------------------------------------------------------
__global__ void ws_guard_kernel(float* out, int n) {
    int i = blockIdx.x * blockDim.x + threadIdx.x;
    if (i < n) out[i] = 1e30f;
}

// ---------------------------------------------------------------------------
// Generic 3D transpose (fp32): in (D0,D1,D2) -> out (D0,D2,D1)
// ---------------------------------------------------------------------------
__global__ void transpose3(const float* __restrict__ in, float* __restrict__ out,
                           int D0, int D1, int D2) {
    int i = blockIdx.x * blockDim.x + threadIdx.x;
    int tot = D0 * D1 * D2;
    if (i >= tot) return;
    int d0 = i / (D1 * D2);
    int r  = i - d0 * (D1 * D2);
    int d1 = r / D2;
    int d2 = r - d1 * D2;
    out[(size_t)d0 * D1 * D2 + (size_t)d2 * D1 + d1] = in[i];
}

// ---------------------------------------------------------------------------
// Pack whh (2,1024,256) fp32 -> (2,256,1024) bf16: out[d][k][j] = bf(in[d][j][k])
// ---------------------------------------------------------------------------
__global__ void pack_whh(const float* __restrict__ in, bf16_t* __restrict__ out) {
    int i = blockIdx.x * 256 + threadIdx.x;       // over 2*256*1024
    int d = i >> 18;
    int r = i & 262143;
    int k = r >> 10;
    int j = r & 1023;
    out[i] = f2bf(in[((size_t)d << 18) + (size_t)j * 256 + k]);
}

// ---------------------------------------------------------------------------
// Tiled fp32-compute GEMM (R3-proven). C = A(row(m)) . W^T + bias, opt relu.
// MODE 1: conv im2col; MODE 2: chunk-fwd; MODE 3: chunk-bwd (time-reversed).
// ---------------------------------------------------------------------------
template <int MODE, int CIN, typename TA, bool OUT_BF>
__global__ __launch_bounds__(256) void gemm_nt(
    const TA* __restrict__ A, const float* __restrict__ W,
    const float* __restrict__ bias, void* __restrict__ Cout,
    int M, int N, int K, int relu, int t0, int chunkM,
    const int* __restrict__ lens)
{
    __shared__ float As[32 * 258];
    __shared__ float Ws[32 * 66];
    const int tid    = threadIdx.x;
    const int m_base = blockIdx.x * 256;
    const int n_base = blockIdx.y * 64;
    const int m0     = (tid >> 3) * 8;
    const int n0     = (tid & 7) * 8;
    float acc[8][8] = {};

    for (int k0 = 0; k0 < K; k0 += 32) {
#pragma unroll
        for (int i = 0; i < 8; ++i) {
            int f4  = i * 256 + tid;
            int row = f4 >> 3;
            int k4  = (f4 & 7) << 2;
            int gm  = m_base + row;
            int gk  = k0 + k4;
            float4 v = make_float4(0.f, 0.f, 0.f, 0.f);
            if (gm < M && gk < K) {
                if constexpr (MODE == 1) {
                    int bb  = gm / T_SEQ;
                    int tt  = gm - bb * T_SEQ;
                    int tap = gk / CIN;
                    int cc  = gk - tap * CIN;
                    int ts  = tt + tap - 1;
                    if (ts >= 0 && ts < T_SEQ)
                        v = ld4(A + ((size_t)(bb * T_SEQ + ts) * CIN + cc));
                } else {
                    int bb = gm / chunkM;
                    int r  = gm - bb * chunkM;
                    int t  = (MODE == 2) ? (t0 + r) : (lens[bb] - 1 - (t0 + r));
                    if (t >= 0 && t < T_SEQ)
                        v = ld4(A + ((size_t)(bb * T_SEQ + t) * K + gk));
                }
            }
            As[(k4 + 0) * 258 + row] = v.x;
            As[(k4 + 1) * 258 + row] = v.y;
            As[(k4 + 2) * 258 + row] = v.z;
            As[(k4 + 3) * 258 + row] = v.w;
        }
#pragma unroll
        for (int i = 0; i < 2; ++i) {
            int f4  = i * 256 + tid;
            int row = f4 >> 3;
            int k4  = (f4 & 7) << 2;
            int gn  = n_base + row;
            int gk  = k0 + k4;
            float4 v = make_float4(0.f, 0.f, 0.f, 0.f);
            if (gk < K)
                v = *(const float4*)(W + (size_t)gn * K + gk);
            Ws[(k4 + 0) * 66 + row] = v.x;
            Ws[(k4 + 1) * 66 + row] = v.y;
            Ws[(k4 + 2) * 66 + row] = v.z;
            Ws[(k4 + 3) * 66 + row] = v.w;
        }
        __syncthreads();
#pragma unroll 8
        for (int kk = 0; kk < 32; ++kk) {
            float am[8], wn[8];
#pragma unroll
            for (int j = 0; j < 4; ++j) {
                float2 a = *(const float2*)(As + kk * 258 + m0 + 2 * j);
                am[2 * j] = a.x; am[2 * j + 1] = a.y;
                float2 w = *(const float2*)(Ws + kk * 66 + n0 + 2 * j);
                wn[2 * j] = w.x; wn[2 * j + 1] = w.y;
            }
#pragma unroll
            for (int im = 0; im < 8; ++im)
#pragma unroll
                for (int in = 0; in < 8; ++in)
                    acc[im][in] = fmaf(am[im], wn[in], acc[im][in]);
        }
        __syncthreads();
    }

    float bs[8];
#pragma unroll
    for (int j = 0; j < 8; ++j) bs[j] = bias[n_base + n0 + j];
#pragma unroll
    for (int im = 0; im < 8; ++im) {
        int gm = m_base + m0 + im;
        if (gm < M) {
            float o[8];
#pragma unroll
            for (int j = 0; j < 8; ++j) {
                float v = acc[im][j] + bs[j];
                o[j] = relu ? fmaxf(v, 0.f) : v;
            }
            if constexpr (OUT_BF) {
                bf16_t* crow = (bf16_t*)Cout + (size_t)gm * N + n_base + n0;
                ushort4 u0 = { f2bf(o[0]), f2bf(o[1]), f2bf(o[2]), f2bf(o[3]) };
                ushort4 u1 = { f2bf(o[4]), f2bf(o[5]), f2bf(o[6]), f2bf(o[7]) };
                *(ushort4*)(crow)     = u0;
                *(ushort4*)(crow + 4) = u1;
            } else {
                float* crow = (float*)Cout + (size_t)gm * N + n_base + n0;
                *(float4*)(crow)     = make_float4(o[0], o[1], o[2], o[3]);
                *(float4*)(crow + 4) = make_float4(o[4], o[5], o[6], o[7]);
            }
        }
    }
}

// ---------------------------------------------------------------------------
// LSTM recurrence, one phase of `chunk` steps. One block (256 thr) per (b,dir)
// chain — no cross-WG communication (R4 lesson). Weights bf16 (2,256,1024),
// gate col j contiguous; thread owns cols j0..j0+3. Weight residency (R5
// lesson: fully resident — don't mix big VGPR arrays with streamed latency):
//   k   0.. 75 : LDS-resident  (152 KB, staged once per phase)
//   k  76..235 : reg-resident  (uint2 wr[160] = 320 regs; AGPR-backed ok)
//   k 236..255 : streamed      (40 KB/step — hidden under ~4.5k cyc VALU)
// h/c/gates fp32; Xp bf16 (prefetched 1 step ahead); Hout bf16.
// ---------------------------------------------------------------------------
#define LDSROWS 76
#define REGROWS 160
__global__ __launch_bounds__(256, 1) void lstm_rec3(
    const bf16_t* __restrict__ XpF, const bf16_t* __restrict__ XpB,
    const bf16_t* __restrict__ whhP,        // (2,256,1024) bf16
    const int* __restrict__ lens,
    float* __restrict__ state,              // (64,512) h|c
    bf16_t* __restrict__ Hout, int s0, int chunk)
{
    extern __shared__ char smem[];
    bf16_t* wl = (bf16_t*)smem;                             // 76*2048 = 155648 B
    float*  hs = (float*)(smem + LDSROWS * 2048);           // 1024 B
    float*  gs = (float*)(smem + LDSROWS * 2048 + 1024);    // 4096 B

    const int bd  = blockIdx.x;
    const int b   = bd >> 1;
    const int d   = bd & 1;
    const int tid = threadIdx.x;
    const int len = lens[b];
    const int s1  = min(s0 + chunk, len);
    const int j0  = tid * 4;
    float* st = state + bd * 512;
    const bf16_t* Wd = whhP + (size_t)d * (256 * 1024);

    // ---- stage LDS rows [0,76): 155648 B = 9728 uint4, 38 per thread ----
    {
        const uint4* src = (const uint4*)Wd;
        uint4* dst = (uint4*)wl;
#pragma unroll
        for (int i = 0; i < 38; ++i)
            dst[i * 256 + tid] = src[i * 256 + tid];
    }
    // ---- stage reg rows [76,236) ----
    uint2 wr[REGROWS];
#pragma unroll
    for (int i = 0; i < REGROWS; ++i)
        wr[i] = *(const uint2*)(Wd + (size_t)(LDSROWS + i) * 1024 + j0);

    float c;
    if (s0 == 0) { hs[tid] = 0.f; c = 0.f; }
    else         { hs[tid] = st[tid]; c = st[256 + tid]; }
    __syncthreads();

    const bf16_t* Xp = (d ? XpB : XpF) + (size_t)b * ((size_t)chunk * 1024);
    float4 xcur = (s0 < s1) ? ld4(Xp + j0) : make_float4(0.f, 0.f, 0.f, 0.f);

    for (int s = s0; s < s1; ++s) {
        float4 acc = xcur;
        if (s + 1 < s1) xcur = ld4(Xp + (size_t)(s + 1 - s0) * 1024 + j0);
        const float4* hq = (const float4*)hs;

        // ---- k 0..75 from LDS (groups of 4 rows share one h float4) ----
#pragma unroll
        for (int g = 0; g < LDSROWS / 4; ++g) {
            float4 h4 = hq[g];
            const float* hp = (const float*)&h4;
#pragma unroll
            for (int u = 0; u < 4; ++u) {
                uint2 w = *(const uint2*)(wl + (g * 4 + u) * 1024 + j0);
                float hk = hp[u];
                acc.x = fmaf(bflo(w.x), hk, acc.x);
                acc.y = fmaf(bfhi(w.x), hk, acc.y);
                acc.z = fmaf(bflo(w.y), hk, acc.z);
                acc.w = fmaf(bfhi(w.y), hk, acc.w);
            }
        }
        // ---- k 76..235 from registers ----
#pragma unroll
        for (int g = 0; g < REGROWS / 4; ++g) {
            float4 h4 = hq[LDSROWS / 4 + g];
            const float* hp = (const float*)&h4;
#pragma unroll
            for (int u = 0; u < 4; ++u) {
                uint2 w = wr[g * 4 + u];
                float hk = hp[u];
                acc.x = fmaf(bflo(w.x), hk, acc.x);
                acc.y = fmaf(bfhi(w.x), hk, acc.y);
                acc.z = fmaf(bflo(w.y), hk, acc.z);
                acc.w = fmaf(bfhi(w.y), hk, acc.w);
            }
        }
        // ---- k 236..255 streamed from L2 ----
#pragma unroll
        for (int g = 0; g < 5; ++g) {
            float4 h4 = hq[(LDSROWS + REGROWS) / 4 + g];
            const float* hp = (const float*)&h4;
#pragma unroll
            for (int u = 0; u < 4; ++u) {
                int k = LDSROWS + REGROWS + g * 4 + u;
                uint2 w = *(const uint2*)(Wd + ((size_t)k << 10) + j0);
                float hk = hp[u];
                acc.x = fmaf(bflo(w.x), hk, acc.x);
                acc.y = fmaf(bfhi(w.x), hk, acc.y);
                acc.z = fmaf(bflo(w.y), hk, acc.z);
                acc.w = fmaf(bfhi(w.y), hk, acc.w);
            }
        }

        *(float4*)(gs + j0) = acc;
        __syncthreads();                    // all matvec reads of hs done too
        float ig = sigmoidf_(gs[tid]);
        float fg = sigmoidf_(gs[256 + tid]);
        float gg = tanh_(gs[512 + tid]);
        float og = sigmoidf_(gs[768 + tid]);
        c = fmaf(fg, c, ig * gg);
        float hn = og * tanh_(c);
        hs[tid] = hn;                       // safe: nobody reads hs until sync
        const int tau = d ? (len - 1 - s) : s;
        Hout[(size_t)(b * T_SEQ + tau) * 512 + (d << 8) + tid] = f2bf(hn);
        __syncthreads();                    // hs stable before next matvec
    }
    st[tid] = hs[tid];
    st[256 + tid] = c;
}

// ---------------------------------------------------------------------------
__global__ __launch_bounds__(256) void pooled_kernel(
    const bf16_t* __restrict__ L, const int* __restrict__ lens,
    float* __restrict__ pooled)
{
    const int b     = blockIdx.x;
    const int chunk = blockIdx.y;
    const int tid   = threadIdx.x;
    const int len   = lens[b];
    const int t0    = chunk * 250;
    const int t1    = min(t0 + 250, len);
    const float inv = 1.f / fmaxf((float)len, 1.f);
    float s0 = 0.f, s1 = 0.f;
    for (int t = t0; t < t1; ++t) {
        const bf16_t* row = L + (size_t)(b * T_SEQ + t) * 512;
        s0 += bf2f(row[tid]);
        s1 += bf2f(row[tid + 256]);
    }
    if (t1 > t0) {
        atomicAdd(&pooled[b * 512 + tid], s0 * inv);
        atomicAdd(&pooled[b * 512 + 256 + tid], s1 * inv);
    }
}

// ---------------------------------------------------------------------------
__global__ __launch_bounds__(256) void utt_head(
    const float* __restrict__ pooled,
    const float* __restrict__ w1T, const float* __restrict__ b1,
    const float* __restrict__ w2, const float* __restrict__ b2,
    float* __restrict__ out)
{
    const int b   = blockIdx.x;
    const int tid = threadIdx.x;
    __shared__ float p[512];
    __shared__ float hid[512];
    __shared__ float red[4];
    p[tid]       = pooled[b * 512 + tid];
    p[tid + 256] = pooled[b * 512 + 256 + tid];
    __syncthreads();
#pragma unroll
    for (int half = 0; half < 2; ++half) {
        int u = tid + half * 256;
        float a = b1[u];
#pragma unroll 8
        for (int k = 0; k < 512; ++k) a = fmaf(w1T[(size_t)k * 512 + u], p[k], a);
        hid[u] = fmaxf(a, 0.f);
    }
    __syncthreads();
    float part = hid[tid] * w2[tid] + hid[tid + 256] * w2[tid + 256];
    for (int off = 32; off; off >>= 1) part += __shfl_down(part, off, 64);
    if ((tid & 63) == 0) red[tid >> 6] = part;
    __syncthreads();
    if (tid == 0) out[b] = red[0] + red[1] + red[2] + red[3] + b2[0];
}

// ---------------------------------------------------------------------------
__global__ __launch_bounds__(256) void seg_head(
    const bf16_t* __restrict__ L, const int* __restrict__ lens,
    const int* __restrict__ segs,
    const float* __restrict__ w1T, const float* __restrict__ b1,
    const float* __restrict__ w2, const float* __restrict__ b2,
    const int* __restrict__ seg_lens, float* __restrict__ out)
{
    const int blk = blockIdx.x;
    const int b   = blk / NSEG;
    const int s   = blk - b * NSEG;
    const int tid = threadIdx.x;
    __shared__ float m[512];
    __shared__ float hid[512];
    __shared__ float red[4];
    const int len = lens[b];
    int st = segs[blk * 2 + 0];
    int en = segs[blk * 2 + 1];
    st = min(max(st, 0), len);
    en = max(st + 1, min(en, len));
    const float inv = 1.f / (float)(en - st);
    float a0 = 0.f, a1 = 0.f;
    for (int t = st; t < en; ++t) {
        const bf16_t* row = L + (size_t)(b * T_SEQ + t) * 512;
        a0 += bf2f(row[tid]);
        a1 += bf2f(row[tid + 256]);
    }
    m[tid]       = a0 * inv;
    m[tid + 256] = a1 * inv;
    __syncthreads();
#pragma unroll
    for (int half = 0; half < 2; ++half) {
        int u = tid + half * 256;
        float a = b1[u];
#pragma unroll 8
        for (int k = 0; k < 512; ++k) a = fmaf(w1T[(size_t)k * 512 + u], m[k], a);
        hid[u] = fmaxf(a, 0.f);
    }
    __syncthreads();
    float part = hid[tid] * w2[tid] + hid[tid + 256] * w2[tid + 256];
    for (int off = 32; off; off >>= 1) part += __shfl_down(part, off, 64);
    if ((tid & 63) == 0) red[tid >> 6] = part;
    __syncthreads();
    if (tid == 0)
        out[BATCH + blk] = (s < seg_lens[b]) ? red[0] + red[1] + red[2] + red[3] + b2[0]
                                             : 0.f;
}

// ---------------------------------------------------------------------------
extern "C" void kernel_launch(void* const* d_in, const int* in_sizes, int n_in,
                              void* d_out, int out_size, void* d_ws, size_t ws_size,
                              hipStream_t stream)
{
    const float* features = (const float*)d_in[0];
    const int*   feat_len = (const int*)d_in[1];
    const int*   segs     = (const int*)d_in[2];
    const int*   seg_lens = (const int*)d_in[3];
    const float* conv1_w  = (const float*)d_in[4];
    const float* conv1_b  = (const float*)d_in[5];
    const float* conv2_w  = (const float*)d_in[6];
    const float* conv2_b  = (const float*)d_in[7];
    const float* wih0     = (const float*)d_in[8];
    const float* whh0     = (const float*)d_in[9];
    const float* bias0    = (const float*)d_in[10];
    const float* wih1     = (const float*)d_in[11];
    const float* whh1     = (const float*)d_in[12];
    const float* bias1    = (const float*)d_in[13];
    const float* seg_w1   = (const float*)d_in[14];
    const float* seg_b1   = (const float*)d_in[15];
    const float* seg_w2   = (const float*)d_in[16];
    const float* seg_b2   = (const float*)d_in[17];
    const float* utt_w1   = (const float*)d_in[18];
    const float* utt_b1   = (const float*)d_in[19];
    const float* utt_w2   = (const float*)d_in[20];
    const float* utt_b2   = (const float*)d_in[21];
    float* out = (float*)d_out;
    char*  wsb = (char*)d_ws;

    // dynamic LDS: 152 KB weights + hs + gs = 160768 B (cap 163840)
    static const size_t REC_LDS = LDSROWS * 2048 + 1024 + 4096;
    hipFuncSetAttribute((const void*)lstm_rec3,
                        hipFuncAttributeMaxDynamicSharedMemorySize, (int)REC_LDS);

    // ---- byte-granular workspace plan (256B-aligned regions) ----
    size_t off = 0;
    auto alloc = [&](size_t bytes) -> size_t {
        size_t o = off;
        off += (bytes + 255) & ~(size_t)255;
        return o;
    };
    const size_t o_wt1    = alloc(61440  * 4);
    const size_t o_wt2    = alloc(196608 * 4);
    const size_t o_sw1T   = alloc(262144 * 4);
    const size_t o_uw1T   = alloc(262144 * 4);
    const size_t o_whh0P  = alloc(524288 * 2);            // bf16 (2,256,1024)
    const size_t o_whh1P  = alloc(524288 * 2);
    const size_t o_state  = alloc(32768 * 4);
    const size_t o_pooled = alloc(16384 * 4);
    const size_t o_Hcat   = alloc((size_t)32768000 * 2);  // bf16 (B,T,512)
    const size_t o_lstm   = alloc((size_t)32768000 * 2);  // bf16 (B,T,512)
    const size_t o_y1     = o_lstm;                        // bf16 (B,T,256) alias
    const size_t o_x2     = o_lstm + (size_t)16384000 * 2; // bf16 (B,T,256) alias
    const size_t fixed_end = off;

    // largest chunk whose bf16 Xp buffers fit
    const int cands[] = {250, 200, 125, 100, 50, 40, 25, 20, 10};
    int chunk = 0;
    size_t o_XpF = 0, o_XpB = 0;
    for (int ci = 0; ci < 9; ++ci) {
        int c = cands[ci];
        size_t xp_bytes = ((size_t)c * 32 * 1024 * 2 + 255) & ~(size_t)255;
        if (fixed_end + 2 * xp_bytes <= ws_size) {
            chunk = c;
            o_XpF = fixed_end;
            o_XpB = fixed_end + xp_bytes;
            break;
        }
    }
    if (chunk == 0) {
        ws_guard_kernel<<<(out_size + 255) / 256, 256, 0, stream>>>(out, out_size);
        return;
    }
    const int nph = T_SEQ / chunk;

    float*   wt1    = (float*)(wsb + o_wt1);
    float*   wt2    = (float*)(wsb + o_wt2);
    float*   sw1T   = (float*)(wsb + o_sw1T);
    float*   uw1T   = (float*)(wsb + o_uw1T);
    bf16_t*  whh0P  = (bf16_t*)(wsb + o_whh0P);
    bf16_t*  whh1P  = (bf16_t*)(wsb + o_whh1P);
    float*   state  = (float*)(wsb + o_state);
    float*   pooled = (float*)(wsb + o_pooled);
    bf16_t*  Hcat   = (bf16_t*)(wsb + o_Hcat);
    bf16_t*  lstm   = (bf16_t*)(wsb + o_lstm);
    bf16_t*  y1     = (bf16_t*)(wsb + o_y1);
    bf16_t*  x2     = (bf16_t*)(wsb + o_x2);
    bf16_t*  XpF    = (bf16_t*)(wsb + o_XpF);
    bf16_t*  XpB    = (bf16_t*)(wsb + o_XpB);

    hipMemsetAsync(state, 0, 32768 * 4, stream);
    hipMemsetAsync(pooled, 0, 16384 * 4, stream);

    transpose3<<<240, 256, 0, stream>>>(conv1_w, wt1, 256, 80, 3);
    transpose3<<<768, 256, 0, stream>>>(conv2_w, wt2, 256, 256, 3);
    transpose3<<<1024, 256, 0, stream>>>(seg_w1, sw1T, 1, 512, 512);
    transpose3<<<1024, 256, 0, stream>>>(utt_w1, uw1T, 1, 512, 512);
    pack_whh<<<2048, 256, 0, stream>>>(whh0, whh0P);
    pack_whh<<<2048, 256, 0, stream>>>(whh1, whh1P);

    // conv1 + conv2 (implicit im2col GEMMs, bf16 outputs)
    gemm_nt<1, 80, float, true><<<dim3(250, 4), 256, 0, stream>>>(
        features, wt1, conv1_b, y1, 64000, 256, 240, 1, 0, 0, feat_len);
    gemm_nt<1, 256, bf16_t, true><<<dim3(250, 4), 256, 0, stream>>>(
        y1, wt2, conv2_b, x2, 64000, 256, 768, 1, 0, 0, feat_len);

    const int gx = (32 * chunk + 255) / 256;

    // ---- layer 0 ----
    for (int p = 0; p < nph; ++p) {
        const int t0 = p * chunk;
        gemm_nt<2, 1, bf16_t, true><<<dim3(gx, 16), 256, 0, stream>>>(
            x2, wih0, bias0, XpF, 32 * chunk, 1024, 256, 0, t0, chunk, feat_len);
        gemm_nt<3, 1, bf16_t, true><<<dim3(gx, 16), 256, 0, stream>>>(
            x2, wih0 + 1024 * 256, bias0 + 1024, XpB, 32 * chunk, 1024, 256, 0,
            t0, chunk, feat_len);
        lstm_rec3<<<64, 256, REC_LDS, stream>>>(
            XpF, XpB, whh0P, feat_len, state, Hcat, t0, chunk);
    }

    // reset recurrent state for layer 1
    hipMemsetAsync(state, 0, 32768 * 4, stream);

    // ---- layer 1 ----
    for (int p = 0; p < nph; ++p) {
        const int t0 = p * chunk;
        gemm_nt<2, 1, bf16_t, true><<<dim3(gx, 16), 256, 0, stream>>>(
            Hcat, wih1, bias1, XpF, 32 * chunk, 1024, 512, 0, t0, chunk, feat_len);
        gemm_nt<3, 1, bf16_t, true><<<dim3(gx, 16), 256, 0, stream>>>(
            Hcat, wih1 + 1024 * 512, bias1 + 1024, XpB, 32 * chunk, 1024, 512, 0,
            t0, chunk, feat_len);
        lstm_rec3<<<64, 256, REC_LDS, stream>>>(
            XpF, XpB, whh1P, feat_len, state, lstm, t0, chunk);  // over dead y1/x2
    }

    pooled_kernel<<<dim3(32, 8), 256, 0, stream>>>(lstm, feat_len, pooled);
    utt_head<<<32, 256, 0, stream>>>(pooled, uw1T, utt_b1, utt_w2, utt_b2, out);
    seg_head<<<3200, 256, 0, stream>>>(lstm, feat_len, segs, sw1T, seg_b1,
                                       seg_w2, seg_b2, seg_lens, out);
}

// Round 7
// 73077.521 us; speedup vs baseline: 1.1519x; 1.1519x over previous
//
#include <hip/hip_runtime.h>
#include <math.h>

#define T_SEQ 2000
#define BATCH 32
#define NSEG  100

typedef unsigned short bf16_t;   // raw bf16 storage

__device__ __forceinline__ float sigmoidf_(float x) {
    return 1.0f / (1.0f + __expf(-x));
}
__device__ __forceinline__ float tanh_(float x) {
    return 1.0f - 2.0f / (__expf(2.0f * x) + 1.0f);
}
__device__ __forceinline__ float bf2f(bf16_t u) {
    return __uint_as_float((unsigned)u << 16);
}
__device__ __forceinline__ bf16_t f2bf(float f) {   // round-to-nearest-even
    unsigned x = __float_as_uint(f);
    return (bf16_t)((x + 0x7FFFu + ((x >> 16) & 1u)) >> 16);
}
__device__ __forceinline__ float bflo(unsigned w) { return __uint_as_float(w << 16); }
__device__ __forceinline__ float bfhi(unsigned w) { return __uint_as_float(w & 0xFFFF0000u); }

// 4 consecutive elements -> float4 (fp32 or bf16 source)
__device__ __forceinline__ float4 ld4(const float* p) { return *(const float4*)p; }
__device__ __forceinline__ float4 ld4(const bf16_t* p) {
    ushort4 u = *(const ushort4*)p;
    return make_float4(bf2f(u.x), bf2f(u.y), bf2f(u.z), bf2f(u.w));
}

// ---------------------------------------------------------------------------
__global__ void ws_guard_kernel(float* out, int n) {
    int i = blockIdx.x * blockDim.x + threadIdx.x;
    if (i < n) out[i] = 1e30f;
}

// ---------------------------------------------------------------------------
// Generic 3D transpose (fp32): in (D0,D1,D2) -> out (D0,D2,D1)
// ---------------------------------------------------------------------------
__global__ void transpose3(const float* __restrict__ in, float* __restrict__ out,
                           int D0, int D1, int D2) {
    int i = blockIdx.x * blockDim.x + threadIdx.x;
    int tot = D0 * D1 * D2;
    if (i >= tot) return;
    int d0 = i / (D1 * D2);
    int r  = i - d0 * (D1 * D2);
    int d1 = r / D2;
    int d2 = r - d1 * D2;
    out[(size_t)d0 * D1 * D2 + (size_t)d2 * D1 + d1] = in[i];
}

// ---------------------------------------------------------------------------
// Gate-interleaved packs. Gate-major (i,f,g,o per jnp.split) -> interleaved
// col' = u*4 + g so a thread owning cols 4u..4u+3 holds dim u's 4 gates.
// ---------------------------------------------------------------------------
// whh (2,1024,256) fp32 -> whhP (2,256,1024) bf16: out[d][k][u*4+g]=in[d][g*256+u][k]
__global__ void pack_whh_gi(const float* __restrict__ in, bf16_t* __restrict__ out) {
    int i = blockIdx.x * 256 + threadIdx.x;       // over 2*256*1024
    int d = i >> 18;
    int r = i & 262143;
    int k = r >> 10;
    int col = r & 1023;
    int u = col >> 2, g = col & 3;
    out[i] = f2bf(in[((size_t)d * 1024 + g * 256 + u) * 256 + k]);
}
// wih (2,1024,K) fp32 -> row-permuted copy: out[d][u*4+g][k] = in[d][g*256+u][k]
__global__ void pack_wih_gi(const float* __restrict__ in, float* __restrict__ out,
                            int K) {
    int i = blockIdx.x * 256 + threadIdx.x;       // over 2*1024*K
    if (i >= 2048 * K) return;
    int d = i / (1024 * K);
    int r = i - d * 1024 * K;
    int n = r / K;
    int k = r - n * K;
    int u = n >> 2, g = n & 3;
    out[i] = in[((size_t)d * 1024 + g * 256 + u) * K + k];
}
// bias (2,1024) -> permuted
__global__ void pack_bias_gi(const float* __restrict__ in, float* __restrict__ out) {
    int i = blockIdx.x * 256 + threadIdx.x;       // 2048
    if (i >= 2048) return;
    int d = i >> 10, n = i & 1023;
    int u = n >> 2, g = n & 3;
    out[i] = in[d * 1024 + g * 256 + u];
}

// ---------------------------------------------------------------------------
// Tiled fp32-compute GEMM (R3-proven). C = A(row(m)) . W^T + bias, opt relu.
// MODE 1: conv im2col; MODE 2: chunk-fwd; MODE 3: chunk-bwd (time-reversed).
// ---------------------------------------------------------------------------
template <int MODE, int CIN, typename TA, bool OUT_BF>
__global__ __launch_bounds__(256) void gemm_nt(
    const TA* __restrict__ A, const float* __restrict__ W,
    const float* __restrict__ bias, void* __restrict__ Cout,
    int M, int N, int K, int relu, int t0, int chunkM,
    const int* __restrict__ lens)
{
    __shared__ float As[32 * 258];
    __shared__ float Ws[32 * 66];
    const int tid    = threadIdx.x;
    const int m_base = blockIdx.x * 256;
    const int n_base = blockIdx.y * 64;
    const int m0     = (tid >> 3) * 8;
    const int n0     = (tid & 7) * 8;
    float acc[8][8] = {};

    for (int k0 = 0; k0 < K; k0 += 32) {
#pragma unroll
        for (int i = 0; i < 8; ++i) {
            int f4  = i * 256 + tid;
            int row = f4 >> 3;
            int k4  = (f4 & 7) << 2;
            int gm  = m_base + row;
            int gk  = k0 + k4;
            float4 v = make_float4(0.f, 0.f, 0.f, 0.f);
            if (gm < M && gk < K) {
                if constexpr (MODE == 1) {
                    int bb  = gm / T_SEQ;
                    int tt  = gm - bb * T_SEQ;
                    int tap = gk / CIN;
                    int cc  = gk - tap * CIN;
                    int ts  = tt + tap - 1;
                    if (ts >= 0 && ts < T_SEQ)
                        v = ld4(A + ((size_t)(bb * T_SEQ + ts) * CIN + cc));
                } else {
                    int bb = gm / chunkM;
                    int r  = gm - bb * chunkM;
                    int t  = (MODE == 2) ? (t0 + r) : (lens[bb] - 1 - (t0 + r));
                    if (t >= 0 && t < T_SEQ)
                        v = ld4(A + ((size_t)(bb * T_SEQ + t) * K + gk));
                }
            }
            As[(k4 + 0) * 258 + row] = v.x;
            As[(k4 + 1) * 258 + row] = v.y;
            As[(k4 + 2) * 258 + row] = v.z;
            As[(k4 + 3) * 258 + row] = v.w;
        }
#pragma unroll
        for (int i = 0; i < 2; ++i) {
            int f4  = i * 256 + tid;
            int row = f4 >> 3;
            int k4  = (f4 & 7) << 2;
            int gn  = n_base + row;
            int gk  = k0 + k4;
            float4 v = make_float4(0.f, 0.f, 0.f, 0.f);
            if (gk < K)
                v = *(const float4*)(W + (size_t)gn * K + gk);
            Ws[(k4 + 0) * 66 + row] = v.x;
            Ws[(k4 + 1) * 66 + row] = v.y;
            Ws[(k4 + 2) * 66 + row] = v.z;
            Ws[(k4 + 3) * 66 + row] = v.w;
        }
        __syncthreads();
#pragma unroll 8
        for (int kk = 0; kk < 32; ++kk) {
            float am[8], wn[8];
#pragma unroll
            for (int j = 0; j < 4; ++j) {
                float2 a = *(const float2*)(As + kk * 258 + m0 + 2 * j);
                am[2 * j] = a.x; am[2 * j + 1] = a.y;
                float2 w = *(const float2*)(Ws + kk * 66 + n0 + 2 * j);
                wn[2 * j] = w.x; wn[2 * j + 1] = w.y;
            }
#pragma unroll
            for (int im = 0; im < 8; ++im)
#pragma unroll
                for (int in = 0; in < 8; ++in)
                    acc[im][in] = fmaf(am[im], wn[in], acc[im][in]);
        }
        __syncthreads();
    }

    float bs[8];
#pragma unroll
    for (int j = 0; j < 8; ++j) bs[j] = bias[n_base + n0 + j];
#pragma unroll
    for (int im = 0; im < 8; ++im) {
        int gm = m_base + m0 + im;
        if (gm < M) {
            float o[8];
#pragma unroll
            for (int j = 0; j < 8; ++j) {
                float v = acc[im][j] + bs[j];
                o[j] = relu ? fmaxf(v, 0.f) : v;
            }
            if constexpr (OUT_BF) {
                bf16_t* crow = (bf16_t*)Cout + (size_t)gm * N + n_base + n0;
                ushort4 u0 = { f2bf(o[0]), f2bf(o[1]), f2bf(o[2]), f2bf(o[3]) };
                ushort4 u1 = { f2bf(o[4]), f2bf(o[5]), f2bf(o[6]), f2bf(o[7]) };
                *(ushort4*)(crow)     = u0;
                *(ushort4*)(crow + 4) = u1;
            } else {
                float* crow = (float*)Cout + (size_t)gm * N + n_base + n0;
                *(float4*)(crow)     = make_float4(o[0], o[1], o[2], o[3]);
                *(float4*)(crow + 4) = make_float4(o[4], o[5], o[6], o[7]);
            }
        }
    }
}

// ---------------------------------------------------------------------------
// LSTM recurrence, one phase of `chunk` steps. One block (256 thr) per (b,dir)
// chain. NO cross-WG sync (R4 lesson), NO per-thread weight arrays (R5/R6
// lesson). Weights bf16 gate-interleaved (2,256,1024):
//   k  0..75  : LDS-resident (152 KB, staged once per phase)
//   k 76..255 : streamed from L2 (360 KB/step; R3-proven pipelined loop)
// Thread tid owns cols 4*tid..4*tid+3 = (i,f,g,o) of hidden dim tid -> gates
// computed in registers, h double-buffered in LDS, ONE sync per step.
// ---------------------------------------------------------------------------
#define LDSROWS 76
__global__ __launch_bounds__(256, 1) void lstm_rec4(
    const bf16_t* __restrict__ XpF, const bf16_t* __restrict__ XpB,
    const bf16_t* __restrict__ whhP,        // (2,256,1024) bf16, gate-interleaved
    const int* __restrict__ lens,
    float* __restrict__ state,              // (64,512) h|c
    bf16_t* __restrict__ Hout, int s0, int chunk)
{
    extern __shared__ char smem[];
    bf16_t* wl = (bf16_t*)smem;                       // 76*2048 = 155648 B
    float*  hs = (float*)(smem + LDSROWS * 2048);     // 2 x 256 floats

    const int bd  = blockIdx.x;
    const int b   = bd >> 1;
    const int d   = bd & 1;
    const int tid = threadIdx.x;
    const int len = lens[b];
    const int s1  = min(s0 + chunk, len);
    const int j0  = tid * 4;
    float* st = state + bd * 512;
    const bf16_t* Wd = whhP + (size_t)d * (256 * 1024);

    // stage LDS rows [0,76): 155648 B = 9728 uint4, 38 per thread
    {
        const uint4* src = (const uint4*)Wd;
        uint4* dst = (uint4*)wl;
#pragma unroll
        for (int i = 0; i < 38; ++i)
            dst[i * 256 + tid] = src[i * 256 + tid];
    }

    int cur = 0;
    float c;
    if (s0 == 0) { hs[tid] = 0.f; c = 0.f; }
    else         { hs[tid] = st[tid]; c = st[256 + tid]; }
    __syncthreads();

    const bf16_t* Xp = (d ? XpB : XpF) + (size_t)b * ((size_t)chunk * 1024);
    float4 xcur = (s0 < s1) ? ld4(Xp + j0) : make_float4(0.f, 0.f, 0.f, 0.f);

    for (int s = s0; s < s1; ++s) {
        float4 acc = xcur;
        if (s + 1 < s1) xcur = ld4(Xp + (size_t)(s + 1 - s0) * 1024 + j0);
        const float4* hq = (const float4*)(hs + cur * 256);

        // ---- k 0..75 from LDS (4-row groups share one h float4 broadcast) ----
#pragma unroll
        for (int g = 0; g < LDSROWS / 4; ++g) {
            float4 h4 = hq[g];
            const float* hp = (const float*)&h4;
#pragma unroll
            for (int u = 0; u < 4; ++u) {
                uint2 w = *(const uint2*)(wl + (g * 4 + u) * 1024 + j0);
                float hk = hp[u];
                acc.x = fmaf(bflo(w.x), hk, acc.x);
                acc.y = fmaf(bfhi(w.x), hk, acc.y);
                acc.z = fmaf(bflo(w.y), hk, acc.z);
                acc.w = fmaf(bfhi(w.y), hk, acc.w);
            }
        }
        // ---- k 76..255 streamed from L2 ----
#pragma unroll 9
        for (int g = LDSROWS / 4; g < 64; ++g) {
            float4 h4 = hq[g];
            const float* hp = (const float*)&h4;
#pragma unroll
            for (int u = 0; u < 4; ++u) {
                uint2 w = *(const uint2*)(Wd + ((size_t)(g * 4 + u) << 10) + j0);
                float hk = hp[u];
                acc.x = fmaf(bflo(w.x), hk, acc.x);
                acc.y = fmaf(bfhi(w.x), hk, acc.y);
                acc.z = fmaf(bflo(w.y), hk, acc.z);
                acc.w = fmaf(bfhi(w.y), hk, acc.w);
            }
        }

        // gates in registers (gate-interleaved layout: acc = i,f,g,o of dim tid)
        float ig = sigmoidf_(acc.x);
        float fg = sigmoidf_(acc.y);
        float gg = tanh_(acc.z);
        float og = sigmoidf_(acc.w);
        c = fmaf(fg, c, ig * gg);
        float hn = og * tanh_(c);
        hs[(cur ^ 1) * 256 + tid] = hn;     // write next buffer; readers are on cur
        const int tau = d ? (len - 1 - s) : s;
        Hout[(size_t)(b * T_SEQ + tau) * 512 + (d << 8) + tid] = f2bf(hn);
        cur ^= 1;
        __syncthreads();                    // single barrier per step
    }
    st[tid] = hs[cur * 256 + tid];
    st[256 + tid] = c;
}

// ---------------------------------------------------------------------------
__global__ __launch_bounds__(256) void pooled_kernel(
    const bf16_t* __restrict__ L, const int* __restrict__ lens,
    float* __restrict__ pooled)
{
    const int b     = blockIdx.x;
    const int chunk = blockIdx.y;
    const int tid   = threadIdx.x;
    const int len   = lens[b];
    const int t0    = chunk * 250;
    const int t1    = min(t0 + 250, len);
    const float inv = 1.f / fmaxf((float)len, 1.f);
    float s0 = 0.f, s1 = 0.f;
    for (int t = t0; t < t1; ++t) {
        const bf16_t* row = L + (size_t)(b * T_SEQ + t) * 512;
        s0 += bf2f(row[tid]);
        s1 += bf2f(row[tid + 256]);
    }
    if (t1 > t0) {
        atomicAdd(&pooled[b * 512 + tid], s0 * inv);
        atomicAdd(&pooled[b * 512 + 256 + tid], s1 * inv);
    }
}

// ---------------------------------------------------------------------------
__global__ __launch_bounds__(256) void utt_head(
    const float* __restrict__ pooled,
    const float* __restrict__ w1T, const float* __restrict__ b1,
    const float* __restrict__ w2, const float* __restrict__ b2,
    float* __restrict__ out)
{
    const int b   = blockIdx.x;
    const int tid = threadIdx.x;
    __shared__ float p[512];
    __shared__ float hid[512];
    __shared__ float red[4];
    p[tid]       = pooled[b * 512 + tid];
    p[tid + 256] = pooled[b * 512 + 256 + tid];
    __syncthreads();
#pragma unroll
    for (int half = 0; half < 2; ++half) {
        int u = tid + half * 256;
        float a = b1[u];
#pragma unroll 8
        for (int k = 0; k < 512; ++k) a = fmaf(w1T[(size_t)k * 512 + u], p[k], a);
        hid[u] = fmaxf(a, 0.f);
    }
    __syncthreads();
    float part = hid[tid] * w2[tid] + hid[tid + 256] * w2[tid + 256];
    for (int off = 32; off; off >>= 1) part += __shfl_down(part, off, 64);
    if ((tid & 63) == 0) red[tid >> 6] = part;
    __syncthreads();
    if (tid == 0) out[b] = red[0] + red[1] + red[2] + red[3] + b2[0];
}

// ---------------------------------------------------------------------------
__global__ __launch_bounds__(256) void seg_head(
    const bf16_t* __restrict__ L, const int* __restrict__ lens,
    const int* __restrict__ segs,
    const float* __restrict__ w1T, const float* __restrict__ b1,
    const float* __restrict__ w2, const float* __restrict__ b2,
    const int* __restrict__ seg_lens, float* __restrict__ out)
{
    const int blk = blockIdx.x;
    const int b   = blk / NSEG;
    const int s   = blk - b * NSEG;
    const int tid = threadIdx.x;
    __shared__ float m[512];
    __shared__ float hid[512];
    __shared__ float red[4];
    const int len = lens[b];
    int st = segs[blk * 2 + 0];
    int en = segs[blk * 2 + 1];
    st = min(max(st, 0), len);
    en = max(st + 1, min(en, len));
    const float inv = 1.f / (float)(en - st);
    float a0 = 0.f, a1 = 0.f;
    for (int t = st; t < en; ++t) {
        const bf16_t* row = L + (size_t)(b * T_SEQ + t) * 512;
        a0 += bf2f(row[tid]);
        a1 += bf2f(row[tid + 256]);
    }
    m[tid]       = a0 * inv;
    m[tid + 256] = a1 * inv;
    __syncthreads();
#pragma unroll
    for (int half = 0; half < 2; ++half) {
        int u = tid + half * 256;
        float a = b1[u];
#pragma unroll 8
        for (int k = 0; k < 512; ++k) a = fmaf(w1T[(size_t)k * 512 + u], m[k], a);
        hid[u] = fmaxf(a, 0.f);
    }
    __syncthreads();
    float part = hid[tid] * w2[tid] + hid[tid + 256] * w2[tid + 256];
    for (int off = 32; off; off >>= 1) part += __shfl_down(part, off, 64);
    if ((tid & 63) == 0) red[tid >> 6] = part;
    __syncthreads();
    if (tid == 0)
        out[BATCH + blk] = (s < seg_lens[b]) ? red[0] + red[1] + red[2] + red[3] + b2[0]
                                             : 0.f;
}

// ---------------------------------------------------------------------------
extern "C" void kernel_launch(void* const* d_in, const int* in_sizes, int n_in,
                              void* d_out, int out_size, void* d_ws, size_t ws_size,
                              hipStream_t stream)
{
    const float* features = (const float*)d_in[0];
    const int*   feat_len = (const int*)d_in[1];
    const int*   segs     = (const int*)d_in[2];
    const int*   seg_lens = (const int*)d_in[3];
    const float* conv1_w  = (const float*)d_in[4];
    const float* conv1_b  = (const float*)d_in[5];
    const float* conv2_w  = (const float*)d_in[6];
    const float* conv2_b  = (const float*)d_in[7];
    const float* wih0     = (const float*)d_in[8];
    const float* whh0     = (const float*)d_in[9];
    const float* bias0    = (const float*)d_in[10];
    const float* wih1     = (const float*)d_in[11];
    const float* whh1     = (const float*)d_in[12];
    const float* bias1    = (const float*)d_in[13];
    const float* seg_w1   = (const float*)d_in[14];
    const float* seg_b1   = (const float*)d_in[15];
    const float* seg_w2   = (const float*)d_in[16];
    const float* seg_b2   = (const float*)d_in[17];
    const float* utt_w1   = (const float*)d_in[18];
    const float* utt_b1   = (const float*)d_in[19];
    const float* utt_w2   = (const float*)d_in[20];
    const float* utt_b2   = (const float*)d_in[21];
    float* out = (float*)d_out;
    char*  wsb = (char*)d_ws;

    // dynamic LDS: 152 KB weights + 2 KB h double buffer
    static const size_t REC_LDS = LDSROWS * 2048 + 2048;
    hipFuncSetAttribute((const void*)lstm_rec4,
                        hipFuncAttributeMaxDynamicSharedMemorySize, (int)REC_LDS);

    // ---- byte-granular workspace plan (256B-aligned regions) ----
    size_t off = 0;
    auto alloc = [&](size_t bytes) -> size_t {
        size_t o = off;
        off += (bytes + 255) & ~(size_t)255;
        return o;
    };
    const size_t o_wt1    = alloc(61440   * 4);
    const size_t o_wt2    = alloc(196608  * 4);
    const size_t o_sw1T   = alloc(262144  * 4);
    const size_t o_uw1T   = alloc(262144  * 4);
    const size_t o_whh0P  = alloc(524288  * 2);           // bf16 gate-interleaved
    const size_t o_whh1P  = alloc(524288  * 2);
    const size_t o_wih0P  = alloc(524288  * 4);           // fp32 row-permuted
    const size_t o_wih1P  = alloc(1048576 * 4);
    const size_t o_b0P    = alloc(2048    * 4);
    const size_t o_b1P    = alloc(2048    * 4);
    const size_t o_state  = alloc(32768   * 4);
    const size_t o_pooled = alloc(16384   * 4);
    const size_t o_Hcat   = alloc((size_t)32768000 * 2);  // bf16 (B,T,512)
    const size_t o_lstm   = alloc((size_t)32768000 * 2);  // bf16 (B,T,512)
    const size_t o_y1     = o_lstm;                        // bf16 (B,T,256) alias
    const size_t o_x2     = o_lstm + (size_t)16384000 * 2; // bf16 (B,T,256) alias
    const size_t fixed_end = off;

    // largest chunk whose bf16 Xp buffers fit
    const int cands[] = {250, 200, 125, 100, 50, 40, 25, 20, 10};
    int chunk = 0;
    size_t o_XpF = 0, o_XpB = 0;
    for (int ci = 0; ci < 9; ++ci) {
        int c = cands[ci];
        size_t xp_bytes = ((size_t)c * 32 * 1024 * 2 + 255) & ~(size_t)255;
        if (fixed_end + 2 * xp_bytes <= ws_size) {
            chunk = c;
            o_XpF = fixed_end;
            o_XpB = fixed_end + xp_bytes;
            break;
        }
    }
    if (chunk == 0) {
        ws_guard_kernel<<<(out_size + 255) / 256, 256, 0, stream>>>(out, out_size);
        return;
    }
    const int nph = T_SEQ / chunk;

    float*   wt1    = (float*)(wsb + o_wt1);
    float*   wt2    = (float*)(wsb + o_wt2);
    float*   sw1T   = (float*)(wsb + o_sw1T);
    float*   uw1T   = (float*)(wsb + o_uw1T);
    bf16_t*  whh0P  = (bf16_t*)(wsb + o_whh0P);
    bf16_t*  whh1P  = (bf16_t*)(wsb + o_whh1P);
    float*   wih0P  = (float*)(wsb + o_wih0P);
    float*   wih1P  = (float*)(wsb + o_wih1P);
    float*   b0P    = (float*)(wsb + o_b0P);
    float*   b1P    = (float*)(wsb + o_b1P);
    float*   state  = (float*)(wsb + o_state);
    float*   pooled = (float*)(wsb + o_pooled);
    bf16_t*  Hcat   = (bf16_t*)(wsb + o_Hcat);
    bf16_t*  lstm   = (bf16_t*)(wsb + o_lstm);
    bf16_t*  y1     = (bf16_t*)(wsb + o_y1);
    bf16_t*  x2     = (bf16_t*)(wsb + o_x2);
    bf16_t*  XpF    = (bf16_t*)(wsb + o_XpF);
    bf16_t*  XpB    = (bf16_t*)(wsb + o_XpB);

    hipMemsetAsync(state, 0, 32768 * 4, stream);
    hipMemsetAsync(pooled, 0, 16384 * 4, stream);

    // weight re-layouts
    transpose3<<<240, 256, 0, stream>>>(conv1_w, wt1, 256, 80, 3);
    transpose3<<<768, 256, 0, stream>>>(conv2_w, wt2, 256, 256, 3);
    transpose3<<<1024, 256, 0, stream>>>(seg_w1, sw1T, 1, 512, 512);
    transpose3<<<1024, 256, 0, stream>>>(utt_w1, uw1T, 1, 512, 512);
    pack_whh_gi<<<2048, 256, 0, stream>>>(whh0, whh0P);
    pack_whh_gi<<<2048, 256, 0, stream>>>(whh1, whh1P);
    pack_wih_gi<<<2048, 256, 0, stream>>>(wih0, wih0P, 256);
    pack_wih_gi<<<4096, 256, 0, stream>>>(wih1, wih1P, 512);
    pack_bias_gi<<<8, 256, 0, stream>>>(bias0, b0P);
    pack_bias_gi<<<8, 256, 0, stream>>>(bias1, b1P);

    // conv1 + conv2 (implicit im2col GEMMs, bf16 outputs)
    gemm_nt<1, 80, float, true><<<dim3(250, 4), 256, 0, stream>>>(
        features, wt1, conv1_b, y1, 64000, 256, 240, 1, 0, 0, feat_len);
    gemm_nt<1, 256, bf16_t, true><<<dim3(250, 4), 256, 0, stream>>>(
        y1, wt2, conv2_b, x2, 64000, 256, 768, 1, 0, 0, feat_len);

    const int gx = (32 * chunk + 255) / 256;

    // ---- layer 0 ----
    for (int p = 0; p < nph; ++p) {
        const int t0 = p * chunk;
        gemm_nt<2, 1, bf16_t, true><<<dim3(gx, 16), 256, 0, stream>>>(
            x2, wih0P, b0P, XpF, 32 * chunk, 1024, 256, 0, t0, chunk, feat_len);
        gemm_nt<3, 1, bf16_t, true><<<dim3(gx, 16), 256, 0, stream>>>(
            x2, wih0P + 1024 * 256, b0P + 1024, XpB, 32 * chunk, 1024, 256, 0,
            t0, chunk, feat_len);
        lstm_rec4<<<64, 256, REC_LDS, stream>>>(
            XpF, XpB, whh0P, feat_len, state, Hcat, t0, chunk);
    }

    // reset recurrent state for layer 1
    hipMemsetAsync(state, 0, 32768 * 4, stream);

    // ---- layer 1 ----
    for (int p = 0; p < nph; ++p) {
        const int t0 = p * chunk;
        gemm_nt<2, 1, bf16_t, true><<<dim3(gx, 16), 256, 0, stream>>>(
            Hcat, wih1P, b1P, XpF, 32 * chunk, 1024, 512, 0, t0, chunk, feat_len);
        gemm_nt<3, 1, bf16_t, true><<<dim3(gx, 16), 256, 0, stream>>>(
            Hcat, wih1P + 1024 * 512, b1P + 1024, XpB, 32 * chunk, 1024, 512, 0,
            t0, chunk, feat_len);
        lstm_rec4<<<64, 256, REC_LDS, stream>>>(
            XpF, XpB, whh1P, feat_len, state, lstm, t0, chunk);  // over dead y1/x2
    }

    pooled_kernel<<<dim3(32, 8), 256, 0, stream>>>(lstm, feat_len, pooled);
    utt_head<<<32, 256, 0, stream>>>(pooled, uw1T, utt_b1, utt_w2, utt_b2, out);
    seg_head<<<3200, 256, 0, stream>>>(lstm, feat_len, segs, sw1T, seg_b1,
                                       seg_w2, seg_b2, seg_lens, out);
}

// Round 8
// 61109.058 us; speedup vs baseline: 1.3775x; 1.1959x over previous
//
#include <hip/hip_runtime.h>
#include <math.h>

#define T_SEQ 2000
#define BATCH 32
#define NSEG  100

typedef unsigned short bf16_t;   // raw bf16 storage

__device__ __forceinline__ float sigmoidf_(float x) {
    return 1.0f / (1.0f + __expf(-x));
}
__device__ __forceinline__ float tanh_(float x) {
    return 1.0f - 2.0f / (__expf(2.0f * x) + 1.0f);
}
__device__ __forceinline__ float bf2f(bf16_t u) {
    return __uint_as_float((unsigned)u << 16);
}
__device__ __forceinline__ bf16_t f2bf(float f) {   // round-to-nearest-even
    unsigned x = __float_as_uint(f);
    return (bf16_t)((x + 0x7FFFu + ((x >> 16) & 1u)) >> 16);
}
__device__ __forceinline__ float bflo(unsigned w) { return __uint_as_float(w << 16); }
__device__ __forceinline__ float bfhi(unsigned w) { return __uint_as_float(w & 0xFFFF0000u); }

// 4 consecutive elements -> float4 (fp32 or bf16 source)
__device__ __forceinline__ float4 ld4(const float* p) { return *(const float4*)p; }
__device__ __forceinline__ float4 ld4(const bf16_t* p) {
    ushort4 u = *(const ushort4*)p;
    return make_float4(bf2f(u.x), bf2f(u.y), bf2f(u.z), bf2f(u.w));
}

// ---------------------------------------------------------------------------
__global__ void ws_guard_kernel(float* out, int n) {
    int i = blockIdx.x * blockDim.x + threadIdx.x;
    if (i < n) out[i] = 1e30f;
}

// ---------------------------------------------------------------------------
// Generic 3D transpose (fp32): in (D0,D1,D2) -> out (D0,D2,D1)
// ---------------------------------------------------------------------------
__global__ void transpose3(const float* __restrict__ in, float* __restrict__ out,
                           int D0, int D1, int D2) {
    int i = blockIdx.x * blockDim.x + threadIdx.x;
    int tot = D0 * D1 * D2;
    if (i >= tot) return;
    int d0 = i / (D1 * D2);
    int r  = i - d0 * (D1 * D2);
    int d1 = r / D2;
    int d2 = r - d1 * D2;
    out[(size_t)d0 * D1 * D2 + (size_t)d2 * D1 + d1] = in[i];
}

// ---------------------------------------------------------------------------
// whh (2,1024,256) fp32 (gate-major rows g*256+u) -> whhQ (2,128,256) uint4.
// Thread t owns gate-interleaved cols 4t..4t+3 = gates (i,f,g,o) of dim t.
// q[d][kp][t] = { pack(i,f)@k=2kp, pack(g,o)@k=2kp, pack(i,f)@k=2kp+1,
//                 pack(g,o)@k=2kp+1 }  (low 16 bits = first element)
// 16-B loads at 4-KB stride in the consumer = R3's proven pipelining shape.
// ---------------------------------------------------------------------------
__global__ void pack_whh_q(const float* __restrict__ in, uint4* __restrict__ out) {
    int i = blockIdx.x * 256 + threadIdx.x;     // over 2*128*256 = 65536
    int d  = i >> 15;
    int r  = i & 32767;
    int kp = r >> 8;
    int t  = r & 255;
    int k0 = kp * 2;
    const float* base = in + (size_t)d * 1024 * 256;
    float v00 = base[((size_t)(0 * 256 + t)) * 256 + k0];
    float v10 = base[((size_t)(1 * 256 + t)) * 256 + k0];
    float v20 = base[((size_t)(2 * 256 + t)) * 256 + k0];
    float v30 = base[((size_t)(3 * 256 + t)) * 256 + k0];
    float v01 = base[((size_t)(0 * 256 + t)) * 256 + k0 + 1];
    float v11 = base[((size_t)(1 * 256 + t)) * 256 + k0 + 1];
    float v21 = base[((size_t)(2 * 256 + t)) * 256 + k0 + 1];
    float v31 = base[((size_t)(3 * 256 + t)) * 256 + k0 + 1];
    uint4 q;
    q.x = (unsigned)f2bf(v00) | ((unsigned)f2bf(v10) << 16);
    q.y = (unsigned)f2bf(v20) | ((unsigned)f2bf(v30) << 16);
    q.z = (unsigned)f2bf(v01) | ((unsigned)f2bf(v11) << 16);
    q.w = (unsigned)f2bf(v21) | ((unsigned)f2bf(v31) << 16);
    out[i] = q;
}

// wih (2,1024,K) fp32 -> row-permuted copy: out[d][u*4+g][k] = in[d][g*256+u][k]
__global__ void pack_wih_gi(const float* __restrict__ in, float* __restrict__ out,
                            int K) {
    int i = blockIdx.x * 256 + threadIdx.x;       // over 2*1024*K
    if (i >= 2048 * K) return;
    int d = i / (1024 * K);
    int r = i - d * 1024 * K;
    int n = r / K;
    int k = r - n * K;
    int u = n >> 2, g = n & 3;
    out[i] = in[((size_t)d * 1024 + g * 256 + u) * K + k];
}
// bias (2,1024) -> permuted
__global__ void pack_bias_gi(const float* __restrict__ in, float* __restrict__ out) {
    int i = blockIdx.x * 256 + threadIdx.x;       // 2048
    if (i >= 2048) return;
    int d = i >> 10, n = i & 1023;
    int u = n >> 2, g = n & 3;
    out[i] = in[d * 1024 + g * 256 + u];
}

// ---------------------------------------------------------------------------
// Tiled fp32-compute GEMM (R3-proven). C = A(row(m)) . W^T + bias, opt relu.
// MODE 1: conv im2col; MODE 2: chunk-fwd; MODE 3: chunk-bwd (time-reversed).
// ---------------------------------------------------------------------------
template <int MODE, int CIN, typename TA, bool OUT_BF>
__global__ __launch_bounds__(256) void gemm_nt(
    const TA* __restrict__ A, const float* __restrict__ W,
    const float* __restrict__ bias, void* __restrict__ Cout,
    int M, int N, int K, int relu, int t0, int chunkM,
    const int* __restrict__ lens)
{
    __shared__ float As[32 * 258];
    __shared__ float Ws[32 * 66];
    const int tid    = threadIdx.x;
    const int m_base = blockIdx.x * 256;
    const int n_base = blockIdx.y * 64;
    const int m0     = (tid >> 3) * 8;
    const int n0     = (tid & 7) * 8;
    float acc[8][8] = {};

    for (int k0 = 0; k0 < K; k0 += 32) {
#pragma unroll
        for (int i = 0; i < 8; ++i) {
            int f4  = i * 256 + tid;
            int row = f4 >> 3;
            int k4  = (f4 & 7) << 2;
            int gm  = m_base + row;
            int gk  = k0 + k4;
            float4 v = make_float4(0.f, 0.f, 0.f, 0.f);
            if (gm < M && gk < K) {
                if constexpr (MODE == 1) {
                    int bb  = gm / T_SEQ;
                    int tt  = gm - bb * T_SEQ;
                    int tap = gk / CIN;
                    int cc  = gk - tap * CIN;
                    int ts  = tt + tap - 1;
                    if (ts >= 0 && ts < T_SEQ)
                        v = ld4(A + ((size_t)(bb * T_SEQ + ts) * CIN + cc));
                } else {
                    int bb = gm / chunkM;
                    int r  = gm - bb * chunkM;
                    int t  = (MODE == 2) ? (t0 + r) : (lens[bb] - 1 - (t0 + r));
                    if (t >= 0 && t < T_SEQ)
                        v = ld4(A + ((size_t)(bb * T_SEQ + t) * K + gk));
                }
            }
            As[(k4 + 0) * 258 + row] = v.x;
            As[(k4 + 1) * 258 + row] = v.y;
            As[(k4 + 2) * 258 + row] = v.z;
            As[(k4 + 3) * 258 + row] = v.w;
        }
#pragma unroll
        for (int i = 0; i < 2; ++i) {
            int f4  = i * 256 + tid;
            int row = f4 >> 3;
            int k4  = (f4 & 7) << 2;
            int gn  = n_base + row;
            int gk  = k0 + k4;
            float4 v = make_float4(0.f, 0.f, 0.f, 0.f);
            if (gk < K)
                v = *(const float4*)(W + (size_t)gn * K + gk);
            Ws[(k4 + 0) * 66 + row] = v.x;
            Ws[(k4 + 1) * 66 + row] = v.y;
            Ws[(k4 + 2) * 66 + row] = v.z;
            Ws[(k4 + 3) * 66 + row] = v.w;
        }
        __syncthreads();
#pragma unroll 8
        for (int kk = 0; kk < 32; ++kk) {
            float am[8], wn[8];
#pragma unroll
            for (int j = 0; j < 4; ++j) {
                float2 a = *(const float2*)(As + kk * 258 + m0 + 2 * j);
                am[2 * j] = a.x; am[2 * j + 1] = a.y;
                float2 w = *(const float2*)(Ws + kk * 66 + n0 + 2 * j);
                wn[2 * j] = w.x; wn[2 * j + 1] = w.y;
            }
#pragma unroll
            for (int im = 0; im < 8; ++im)
#pragma unroll
                for (int in = 0; in < 8; ++in)
                    acc[im][in] = fmaf(am[im], wn[in], acc[im][in]);
        }
        __syncthreads();
    }

    float bs[8];
#pragma unroll
    for (int j = 0; j < 8; ++j) bs[j] = bias[n_base + n0 + j];
#pragma unroll
    for (int im = 0; im < 8; ++im) {
        int gm = m_base + m0 + im;
        if (gm < M) {
            float o[8];
#pragma unroll
            for (int j = 0; j < 8; ++j) {
                float v = acc[im][j] + bs[j];
                o[j] = relu ? fmaxf(v, 0.f) : v;
            }
            if constexpr (OUT_BF) {
                bf16_t* crow = (bf16_t*)Cout + (size_t)gm * N + n_base + n0;
                ushort4 u0 = { f2bf(o[0]), f2bf(o[1]), f2bf(o[2]), f2bf(o[3]) };
                ushort4 u1 = { f2bf(o[4]), f2bf(o[5]), f2bf(o[6]), f2bf(o[7]) };
                *(ushort4*)(crow)     = u0;
                *(ushort4*)(crow + 4) = u1;
            } else {
                float* crow = (float*)Cout + (size_t)gm * N + n_base + n0;
                *(float4*)(crow)     = make_float4(o[0], o[1], o[2], o[3]);
                *(float4*)(crow + 4) = make_float4(o[4], o[5], o[6], o[7]);
            }
        }
    }
}

// ---------------------------------------------------------------------------
// LSTM recurrence, one phase of `chunk` steps. One block (256 thr) per (b,dir)
// chain. Constraints proven so far: no cross-WG sync (R4), no per-thread
// weight arrays (R5/R6), streamed loads MUST be 16-B at 4-KB stride (R3 fast
// vs R5/R7 slow). whhQ (2,128,256) uint4: one load = thread's 4 gate-
// interleaved cols x 2 consecutive k-rows.
//   kp  0..37  : LDS-resident (152 KB, staged once per phase)
//   kp 38..127 : streamed from L2 (90 x 16-B loads, 360 KB/step)
// Gates computed in registers; h double-buffered in LDS; ONE barrier/step.
// ---------------------------------------------------------------------------
#define LDSPAIRS 38
__global__ __launch_bounds__(256, 1) void lstm_rec5(
    const bf16_t* __restrict__ XpF, const bf16_t* __restrict__ XpB,
    const uint4* __restrict__ whhQ,         // (2,128,256) uint4
    const int* __restrict__ lens,
    float* __restrict__ state,              // (64,512) h|c
    bf16_t* __restrict__ Hout, int s0, int chunk)
{
    extern __shared__ char smem[];
    uint4* wl = (uint4*)smem;                         // 38*256 uint4 = 155648 B
    float* hs = (float*)(smem + LDSPAIRS * 256 * 16); // 2 x 256 floats

    const int bd  = blockIdx.x;
    const int b   = bd >> 1;
    const int d   = bd & 1;
    const int tid = threadIdx.x;
    const int len = lens[b];
    const int s1  = min(s0 + chunk, len);
    float* st = state + bd * 512;
    const uint4* Wd = whhQ + (size_t)d * (128 * 256);

    // stage kp 0..37 into LDS
#pragma unroll
    for (int i = 0; i < LDSPAIRS; ++i)
        wl[i * 256 + tid] = Wd[i * 256 + tid];

    int cur = 0;
    float c;
    if (s0 == 0) { hs[tid] = 0.f; c = 0.f; }
    else         { hs[tid] = st[tid]; c = st[256 + tid]; }
    __syncthreads();

    const bf16_t* Xp = (d ? XpB : XpF) + (size_t)b * ((size_t)chunk * 1024);
    const int j0 = tid * 4;
    float4 xcur = (s0 < s1) ? ld4(Xp + j0) : make_float4(0.f, 0.f, 0.f, 0.f);

    for (int s = s0; s < s1; ++s) {
        float4 acc = xcur;
        if (s + 1 < s1) xcur = ld4(Xp + (size_t)(s + 1 - s0) * 1024 + j0);
        const float* hp = hs + cur * 256;

        // ---- kp 0..37 from LDS ----
#pragma unroll
        for (int kp = 0; kp < LDSPAIRS; ++kp) {
            uint4 w = wl[kp * 256 + tid];
            float h0 = hp[2 * kp];
            float h1 = hp[2 * kp + 1];
            acc.x = fmaf(bflo(w.x), h0, acc.x);
            acc.y = fmaf(bfhi(w.x), h0, acc.y);
            acc.z = fmaf(bflo(w.y), h0, acc.z);
            acc.w = fmaf(bfhi(w.y), h0, acc.w);
            acc.x = fmaf(bflo(w.z), h1, acc.x);
            acc.y = fmaf(bfhi(w.z), h1, acc.y);
            acc.z = fmaf(bflo(w.w), h1, acc.z);
            acc.w = fmaf(bfhi(w.w), h1, acc.w);
        }
        // ---- kp 38..127 streamed (16-B loads, 4-KB stride — R3 shape) ----
#pragma unroll 15
        for (int kp = LDSPAIRS; kp < 128; ++kp) {
            uint4 w = Wd[kp * 256 + tid];
            float h0 = hp[2 * kp];
            float h1 = hp[2 * kp + 1];
            acc.x = fmaf(bflo(w.x), h0, acc.x);
            acc.y = fmaf(bfhi(w.x), h0, acc.y);
            acc.z = fmaf(bflo(w.y), h0, acc.z);
            acc.w = fmaf(bfhi(w.y), h0, acc.w);
            acc.x = fmaf(bflo(w.z), h1, acc.x);
            acc.y = fmaf(bfhi(w.z), h1, acc.y);
            acc.z = fmaf(bflo(w.w), h1, acc.z);
            acc.w = fmaf(bfhi(w.w), h1, acc.w);
        }

        // gates in registers (acc = i,f,g,o of hidden dim tid)
        float ig = sigmoidf_(acc.x);
        float fg = sigmoidf_(acc.y);
        float gg = tanh_(acc.z);
        float og = sigmoidf_(acc.w);
        c = fmaf(fg, c, ig * gg);
        float hn = og * tanh_(c);
        hs[(cur ^ 1) * 256 + tid] = hn;     // write next buffer
        const int tau = d ? (len - 1 - s) : s;
        Hout[(size_t)(b * T_SEQ + tau) * 512 + (d << 8) + tid] = f2bf(hn);
        cur ^= 1;
        __syncthreads();                    // single barrier per step
    }
    st[tid] = hs[cur * 256 + tid];
    st[256 + tid] = c;
}

// ---------------------------------------------------------------------------
__global__ __launch_bounds__(256) void pooled_kernel(
    const bf16_t* __restrict__ L, const int* __restrict__ lens,
    float* __restrict__ pooled)
{
    const int b     = blockIdx.x;
    const int chunk = blockIdx.y;
    const int tid   = threadIdx.x;
    const int len   = lens[b];
    const int t0    = chunk * 250;
    const int t1    = min(t0 + 250, len);
    const float inv = 1.f / fmaxf((float)len, 1.f);
    float s0 = 0.f, s1 = 0.f;
    for (int t = t0; t < t1; ++t) {
        const bf16_t* row = L + (size_t)(b * T_SEQ + t) * 512;
        s0 += bf2f(row[tid]);
        s1 += bf2f(row[tid + 256]);
    }
    if (t1 > t0) {
        atomicAdd(&pooled[b * 512 + tid], s0 * inv);
        atomicAdd(&pooled[b * 512 + 256 + tid], s1 * inv);
    }
}

// ---------------------------------------------------------------------------
__global__ __launch_bounds__(256) void utt_head(
    const float* __restrict__ pooled,
    const float* __restrict__ w1T, const float* __restrict__ b1,
    const float* __restrict__ w2, const float* __restrict__ b2,
    float* __restrict__ out)
{
    const int b   = blockIdx.x;
    const int tid = threadIdx.x;
    __shared__ float p[512];
    __shared__ float hid[512];
    __shared__ float red[4];
    p[tid]       = pooled[b * 512 + tid];
    p[tid + 256] = pooled[b * 512 + 256 + tid];
    __syncthreads();
#pragma unroll
    for (int half = 0; half < 2; ++half) {
        int u = tid + half * 256;
        float a = b1[u];
#pragma unroll 8
        for (int k = 0; k < 512; ++k) a = fmaf(w1T[(size_t)k * 512 + u], p[k], a);
        hid[u] = fmaxf(a, 0.f);
    }
    __syncthreads();
    float part = hid[tid] * w2[tid] + hid[tid + 256] * w2[tid + 256];
    for (int off = 32; off; off >>= 1) part += __shfl_down(part, off, 64);
    if ((tid & 63) == 0) red[tid >> 6] = part;
    __syncthreads();
    if (tid == 0) out[b] = red[0] + red[1] + red[2] + red[3] + b2[0];
}

// ---------------------------------------------------------------------------
__global__ __launch_bounds__(256) void seg_head(
    const bf16_t* __restrict__ L, const int* __restrict__ lens,
    const int* __restrict__ segs,
    const float* __restrict__ w1T, const float* __restrict__ b1,
    const float* __restrict__ w2, const float* __restrict__ b2,
    const int* __restrict__ seg_lens, float* __restrict__ out)
{
    const int blk = blockIdx.x;
    const int b   = blk / NSEG;
    const int s   = blk - b * NSEG;
    const int tid = threadIdx.x;
    __shared__ float m[512];
    __shared__ float hid[512];
    __shared__ float red[4];
    const int len = lens[b];
    int st = segs[blk * 2 + 0];
    int en = segs[blk * 2 + 1];
    st = min(max(st, 0), len);
    en = max(st + 1, min(en, len));
    const float inv = 1.f / (float)(en - st);
    float a0 = 0.f, a1 = 0.f;
    for (int t = st; t < en; ++t) {
        const bf16_t* row = L + (size_t)(b * T_SEQ + t) * 512;
        a0 += bf2f(row[tid]);
        a1 += bf2f(row[tid + 256]);
    }
    m[tid]       = a0 * inv;
    m[tid + 256] = a1 * inv;
    __syncthreads();
#pragma unroll
    for (int half = 0; half < 2; ++half) {
        int u = tid + half * 256;
        float a = b1[u];
#pragma unroll 8
        for (int k = 0; k < 512; ++k) a = fmaf(w1T[(size_t)k * 512 + u], m[k], a);
        hid[u] = fmaxf(a, 0.f);
    }
    __syncthreads();
    float part = hid[tid] * w2[tid] + hid[tid + 256] * w2[tid + 256];
    for (int off = 32; off; off >>= 1) part += __shfl_down(part, off, 64);
    if ((tid & 63) == 0) red[tid >> 6] = part;
    __syncthreads();
    if (tid == 0)
        out[BATCH + blk] = (s < seg_lens[b]) ? red[0] + red[1] + red[2] + red[3] + b2[0]
                                             : 0.f;
}

// ---------------------------------------------------------------------------
extern "C" void kernel_launch(void* const* d_in, const int* in_sizes, int n_in,
                              void* d_out, int out_size, void* d_ws, size_t ws_size,
                              hipStream_t stream)
{
    const float* features = (const float*)d_in[0];
    const int*   feat_len = (const int*)d_in[1];
    const int*   segs     = (const int*)d_in[2];
    const int*   seg_lens = (const int*)d_in[3];
    const float* conv1_w  = (const float*)d_in[4];
    const float* conv1_b  = (const float*)d_in[5];
    const float* conv2_w  = (const float*)d_in[6];
    const float* conv2_b  = (const float*)d_in[7];
    const float* wih0     = (const float*)d_in[8];
    const float* whh0     = (const float*)d_in[9];
    const float* bias0    = (const float*)d_in[10];
    const float* wih1     = (const float*)d_in[11];
    const float* whh1     = (const float*)d_in[12];
    const float* bias1    = (const float*)d_in[13];
    const float* seg_w1   = (const float*)d_in[14];
    const float* seg_b1   = (const float*)d_in[15];
    const float* seg_w2   = (const float*)d_in[16];
    const float* seg_b2   = (const float*)d_in[17];
    const float* utt_w1   = (const float*)d_in[18];
    const float* utt_b1   = (const float*)d_in[19];
    const float* utt_w2   = (const float*)d_in[20];
    const float* utt_b2   = (const float*)d_in[21];
    float* out = (float*)d_out;
    char*  wsb = (char*)d_ws;

    // dynamic LDS: 152 KB weights + 2 KB h double buffer
    static const size_t REC_LDS = LDSPAIRS * 256 * 16 + 2048;
    hipFuncSetAttribute((const void*)lstm_rec5,
                        hipFuncAttributeMaxDynamicSharedMemorySize, (int)REC_LDS);

    // ---- byte-granular workspace plan (256B-aligned regions) ----
    size_t off = 0;
    auto alloc = [&](size_t bytes) -> size_t {
        size_t o = off;
        off += (bytes + 255) & ~(size_t)255;
        return o;
    };
    const size_t o_wt1    = alloc(61440   * 4);
    const size_t o_wt2    = alloc(196608  * 4);
    const size_t o_sw1T   = alloc(262144  * 4);
    const size_t o_uw1T   = alloc(262144  * 4);
    const size_t o_whh0Q  = alloc(65536   * 16);          // (2,128,256) uint4
    const size_t o_whh1Q  = alloc(65536   * 16);
    const size_t o_wih0P  = alloc(524288  * 4);           // fp32 row-permuted
    const size_t o_wih1P  = alloc(1048576 * 4);
    const size_t o_b0P    = alloc(2048    * 4);
    const size_t o_b1P    = alloc(2048    * 4);
    const size_t o_state  = alloc(32768   * 4);
    const size_t o_pooled = alloc(16384   * 4);
    const size_t o_Hcat   = alloc((size_t)32768000 * 2);  // bf16 (B,T,512)
    const size_t o_lstm   = alloc((size_t)32768000 * 2);  // bf16 (B,T,512)
    const size_t o_y1     = o_lstm;                        // bf16 (B,T,256) alias
    const size_t o_x2     = o_lstm + (size_t)16384000 * 2; // bf16 (B,T,256) alias
    const size_t fixed_end = off;

    // largest chunk whose bf16 Xp buffers fit
    const int cands[] = {250, 200, 125, 100, 50, 40, 25, 20, 10};
    int chunk = 0;
    size_t o_XpF = 0, o_XpB = 0;
    for (int ci = 0; ci < 9; ++ci) {
        int c = cands[ci];
        size_t xp_bytes = ((size_t)c * 32 * 1024 * 2 + 255) & ~(size_t)255;
        if (fixed_end + 2 * xp_bytes <= ws_size) {
            chunk = c;
            o_XpF = fixed_end;
            o_XpB = fixed_end + xp_bytes;
            break;
        }
    }
    if (chunk == 0) {
        ws_guard_kernel<<<(out_size + 255) / 256, 256, 0, stream>>>(out, out_size);
        return;
    }
    const int nph = T_SEQ / chunk;

    float*   wt1    = (float*)(wsb + o_wt1);
    float*   wt2    = (float*)(wsb + o_wt2);
    float*   sw1T   = (float*)(wsb + o_sw1T);
    float*   uw1T   = (float*)(wsb + o_uw1T);
    uint4*   whh0Q  = (uint4*)(wsb + o_whh0Q);
    uint4*   whh1Q  = (uint4*)(wsb + o_whh1Q);
    float*   wih0P  = (float*)(wsb + o_wih0P);
    float*   wih1P  = (float*)(wsb + o_wih1P);
    float*   b0P    = (float*)(wsb + o_b0P);
    float*   b1P    = (float*)(wsb + o_b1P);
    float*   state  = (float*)(wsb + o_state);
    float*   pooled = (float*)(wsb + o_pooled);
    bf16_t*  Hcat   = (bf16_t*)(wsb + o_Hcat);
    bf16_t*  lstm   = (bf16_t*)(wsb + o_lstm);
    bf16_t*  y1     = (bf16_t*)(wsb + o_y1);
    bf16_t*  x2     = (bf16_t*)(wsb + o_x2);
    bf16_t*  XpF    = (bf16_t*)(wsb + o_XpF);
    bf16_t*  XpB    = (bf16_t*)(wsb + o_XpB);

    hipMemsetAsync(state, 0, 32768 * 4, stream);
    hipMemsetAsync(pooled, 0, 16384 * 4, stream);

    // weight re-layouts
    transpose3<<<240, 256, 0, stream>>>(conv1_w, wt1, 256, 80, 3);
    transpose3<<<768, 256, 0, stream>>>(conv2_w, wt2, 256, 256, 3);
    transpose3<<<1024, 256, 0, stream>>>(seg_w1, sw1T, 1, 512, 512);
    transpose3<<<1024, 256, 0, stream>>>(utt_w1, uw1T, 1, 512, 512);
    pack_whh_q<<<256, 256, 0, stream>>>(whh0, whh0Q);
    pack_whh_q<<<256, 256, 0, stream>>>(whh1, whh1Q);
    pack_wih_gi<<<2048, 256, 0, stream>>>(wih0, wih0P, 256);
    pack_wih_gi<<<4096, 256, 0, stream>>>(wih1, wih1P, 512);
    pack_bias_gi<<<8, 256, 0, stream>>>(bias0, b0P);
    pack_bias_gi<<<8, 256, 0, stream>>>(bias1, b1P);

    // conv1 + conv2 (implicit im2col GEMMs, bf16 outputs)
    gemm_nt<1, 80, float, true><<<dim3(250, 4), 256, 0, stream>>>(
        features, wt1, conv1_b, y1, 64000, 256, 240, 1, 0, 0, feat_len);
    gemm_nt<1, 256, bf16_t, true><<<dim3(250, 4), 256, 0, stream>>>(
        y1, wt2, conv2_b, x2, 64000, 256, 768, 1, 0, 0, feat_len);

    const int gx = (32 * chunk + 255) / 256;

    // ---- layer 0 ----
    for (int p = 0; p < nph; ++p) {
        const int t0 = p * chunk;
        gemm_nt<2, 1, bf16_t, true><<<dim3(gx, 16), 256, 0, stream>>>(
            x2, wih0P, b0P, XpF, 32 * chunk, 1024, 256, 0, t0, chunk, feat_len);
        gemm_nt<3, 1, bf16_t, true><<<dim3(gx, 16), 256, 0, stream>>>(
            x2, wih0P + 1024 * 256, b0P + 1024, XpB, 32 * chunk, 1024, 256, 0,
            t0, chunk, feat_len);
        lstm_rec5<<<64, 256, REC_LDS, stream>>>(
            XpF, XpB, whh0Q, feat_len, state, Hcat, t0, chunk);
    }

    // reset recurrent state for layer 1
    hipMemsetAsync(state, 0, 32768 * 4, stream);

    // ---- layer 1 ----
    for (int p = 0; p < nph; ++p) {
        const int t0 = p * chunk;
        gemm_nt<2, 1, bf16_t, true><<<dim3(gx, 16), 256, 0, stream>>>(
            Hcat, wih1P, b1P, XpF, 32 * chunk, 1024, 512, 0, t0, chunk, feat_len);
        gemm_nt<3, 1, bf16_t, true><<<dim3(gx, 16), 256, 0, stream>>>(
            Hcat, wih1P + 1024 * 512, b1P + 1024, XpB, 32 * chunk, 1024, 512, 0,
            t0, chunk, feat_len);
        lstm_rec5<<<64, 256, REC_LDS, stream>>>(
            XpF, XpB, whh1Q, feat_len, state, lstm, t0, chunk);  // over dead y1/x2
    }

    pooled_kernel<<<dim3(32, 8), 256, 0, stream>>>(lstm, feat_len, pooled);
    utt_head<<<32, 256, 0, stream>>>(pooled, uw1T, utt_b1, utt_w2, utt_b2, out);
    seg_head<<<3200, 256, 0, stream>>>(lstm, feat_len, segs, sw1T, seg_b1,
                                       seg_w2, seg_b2, seg_lens, out);
}